// Round 4
// baseline (154.862 us; speedup 1.0000x reference)
//
#include <hip/hip_runtime.h>

#define N_NODES 50000
#define F_IN 64
#define F_OUT 128
#define N_EDGES 800000

#define NPART 8          // slot partitions (~XCD-private under round-robin dispatch)
#define CAPP 24          // slots per node per partition; P(Poisson(2) > 24) ~ 1e-18
#define BUCKET_BLOCKS 1024
#define GROWS 16
#define GEMM_BLOCKS (N_NODES / GROWS)   // 3125

__device__ __forceinline__ unsigned short f2bf(float f) {
  unsigned u = __float_as_uint(f);
  unsigned r = u + 0x7FFF + ((u >> 16) & 1);   // round-to-nearest-even
  return (unsigned short)(r >> 16);
}
__device__ __forceinline__ float bf2f(unsigned short h) {
  return __uint_as_float((unsigned)h << 16);
}

// ---------------------------------------------------------------------------
// One launch, two block roles (disjoint inputs -> concurrent execution):
//  blocks [0, BUCKET_BLOCKS)            : bucket edges by destination row
//  blocks [BUCKET_BLOCKS, +GEMM_BLOCKS) : P/Q node projections
//
// Bucket: partition by blockIdx&7 so each ~XCD writes a private 2.4 MB slot
// region (stays in its local L2; no cross-XCD 64B-line false sharing).
// int64-vs-int32 edge layout detected from words 1..7 (odd words all zero
// for int64 LE values < 2^31; ~(2e-5)^4 false-positive for int32).
//
// GEMM: P[n] = (W1 - W2).x[n] + b (f32), Qb[n] = W2.x[n] (bf16).
// x rows are read at wave-uniform addresses straight from global -> scalar
// loads (SGPR) feeding v_fma; weight column lives in 64 VGPRs; 4 independent
// row accumulator chains hide VALU latency. No LDS, no barriers.
// ---------------------------------------------------------------------------
__global__ __launch_bounds__(256) void fused_gemm_bucket_kernel(
    const float* __restrict__ x, const float* __restrict__ W,
    const float* __restrict__ b, const unsigned int* __restrict__ eraw,
    float* __restrict__ P, unsigned short* __restrict__ Qb,
    int* __restrict__ cnt, unsigned short* __restrict__ slots) {
  if (blockIdx.x < BUCKET_BLOCKS) {
    const int part = blockIdx.x & (NPART - 1);
    const bool is64 = ((eraw[1] | eraw[3] | eraw[5] | eraw[7]) == 0u);
    const int stride = BUCKET_BLOCKS * 256;
    for (int e = blockIdx.x * 256 + threadIdx.x; e < N_EDGES; e += stride) {
      int r = (int)(is64 ? eraw[2 * (size_t)e] : eraw[e]);
      int c = (int)(is64 ? eraw[2 * ((size_t)N_EDGES + e)] : eraw[N_EDGES + e]);
      int pos = atomicAdd(&cnt[part * N_NODES + r], 1);
      if (pos < CAPP)
        slots[((size_t)part * N_NODES + r) * CAPP + pos] = (unsigned short)c;
    }
    return;
  }

  const int gb = blockIdx.x - BUCKET_BLOCKS;
  const int row0 = gb * GROWS;
  const int j = threadIdx.x;

  float wcol[F_IN];
  if (j < F_OUT) {
#pragma unroll
    for (int k4 = 0; k4 < F_IN / 4; ++k4) {
      float4 w1 = *(const float4*)&W[j * (2 * F_IN) + k4 * 4];
      float4 w2 = *(const float4*)&W[j * (2 * F_IN) + F_IN + k4 * 4];
      wcol[k4 * 4 + 0] = w1.x - w2.x; wcol[k4 * 4 + 1] = w1.y - w2.y;
      wcol[k4 * 4 + 2] = w1.z - w2.z; wcol[k4 * 4 + 3] = w1.w - w2.w;
    }
  } else {
#pragma unroll
    for (int k4 = 0; k4 < F_IN / 4; ++k4) {
      float4 w2 = *(const float4*)&W[(j - F_OUT) * (2 * F_IN) + F_IN + k4 * 4];
      wcol[k4 * 4 + 0] = w2.x; wcol[k4 * 4 + 1] = w2.y;
      wcol[k4 * 4 + 2] = w2.z; wcol[k4 * 4 + 3] = w2.w;
    }
  }
  const float bias = (j < F_OUT) ? b[j] : 0.f;
  const int jj = (j < F_OUT) ? j : j - F_OUT;
  const float* __restrict__ xr = x + (size_t)row0 * F_IN;   // wave-uniform base

  for (int r0 = 0; r0 < GROWS; r0 += 4) {
    float s0 = bias, s1 = bias, s2 = bias, s3 = bias;
#pragma unroll
    for (int k4 = 0; k4 < F_IN / 4; ++k4) {
      // wave-uniform addresses -> scalar (SGPR) loads through the k-cache
      float4 a0 = *(const float4*)&xr[(r0 + 0) * F_IN + k4 * 4];
      float4 a1 = *(const float4*)&xr[(r0 + 1) * F_IN + k4 * 4];
      float4 a2 = *(const float4*)&xr[(r0 + 2) * F_IN + k4 * 4];
      float4 a3 = *(const float4*)&xr[(r0 + 3) * F_IN + k4 * 4];
      const float w0 = wcol[k4 * 4], w1 = wcol[k4 * 4 + 1];
      const float w2 = wcol[k4 * 4 + 2], w3 = wcol[k4 * 4 + 3];
      s0 = fmaf(a0.x, w0, s0); s1 = fmaf(a1.x, w0, s1);
      s2 = fmaf(a2.x, w0, s2); s3 = fmaf(a3.x, w0, s3);
      s0 = fmaf(a0.y, w1, s0); s1 = fmaf(a1.y, w1, s1);
      s2 = fmaf(a2.y, w1, s2); s3 = fmaf(a3.y, w1, s3);
      s0 = fmaf(a0.z, w2, s0); s1 = fmaf(a1.z, w2, s1);
      s2 = fmaf(a2.z, w2, s2); s3 = fmaf(a3.z, w2, s3);
      s0 = fmaf(a0.w, w3, s0); s1 = fmaf(a1.w, w3, s1);
      s2 = fmaf(a2.w, w3, s2); s3 = fmaf(a3.w, w3, s3);
    }
    if (j < F_OUT) {
      P[(size_t)(row0 + r0 + 0) * F_OUT + jj] = s0;
      P[(size_t)(row0 + r0 + 1) * F_OUT + jj] = s1;
      P[(size_t)(row0 + r0 + 2) * F_OUT + jj] = s2;
      P[(size_t)(row0 + r0 + 3) * F_OUT + jj] = s3;
    } else {
      Qb[(size_t)(row0 + r0 + 0) * F_OUT + jj] = f2bf(s0);
      Qb[(size_t)(row0 + r0 + 1) * F_OUT + jj] = f2bf(s1);
      Qb[(size_t)(row0 + r0 + 2) * F_OUT + jj] = f2bf(s2);
      Qb[(size_t)(row0 + r0 + 3) * F_OUT + jj] = f2bf(s3);
    }
  }
}

// ---------------------------------------------------------------------------
// Per node n: out[n] = (1/max(deg,1)) * sum over partitions/slots of
// relu(P[n] + Q[col]). 32 lanes per node (float4 each), 8 nodes per block.
// ---------------------------------------------------------------------------
__global__ __launch_bounds__(256) void aggregate_kernel(
    const float* __restrict__ P, const unsigned short* __restrict__ Qb,
    const unsigned short* __restrict__ slots, const int* __restrict__ cnt,
    float* __restrict__ out) {
  const int tid = threadIdx.x;
  const int lane = tid & 31;
  const int n = blockIdx.x * 8 + (tid >> 5);   // grid covers exactly N_NODES

  const float4 p = ((const float4*)(P + (size_t)n * F_OUT))[lane];
  float4 acc = make_float4(0.f, 0.f, 0.f, 0.f);
  int deg = 0;

#pragma unroll
  for (int part = 0; part < NPART; ++part) {
    const int c = cnt[part * N_NODES + n];
    deg += c;
    const int m = min(c, CAPP);
    const unsigned short* sl = slots + ((size_t)part * N_NODES + n) * CAPP;
    int j = 0;
    for (; j + 4 <= m; j += 4) {
      ushort4 cs = *(const ushort4*)(sl + j);
      ushort4 q0 = ((const ushort4*)(Qb + (size_t)cs.x * F_OUT))[lane];
      ushort4 q1 = ((const ushort4*)(Qb + (size_t)cs.y * F_OUT))[lane];
      ushort4 q2 = ((const ushort4*)(Qb + (size_t)cs.z * F_OUT))[lane];
      ushort4 q3 = ((const ushort4*)(Qb + (size_t)cs.w * F_OUT))[lane];
      acc.x += fmaxf(p.x + bf2f(q0.x), 0.f); acc.y += fmaxf(p.y + bf2f(q0.y), 0.f);
      acc.z += fmaxf(p.z + bf2f(q0.z), 0.f); acc.w += fmaxf(p.w + bf2f(q0.w), 0.f);
      acc.x += fmaxf(p.x + bf2f(q1.x), 0.f); acc.y += fmaxf(p.y + bf2f(q1.y), 0.f);
      acc.z += fmaxf(p.z + bf2f(q1.z), 0.f); acc.w += fmaxf(p.w + bf2f(q1.w), 0.f);
      acc.x += fmaxf(p.x + bf2f(q2.x), 0.f); acc.y += fmaxf(p.y + bf2f(q2.y), 0.f);
      acc.z += fmaxf(p.z + bf2f(q2.z), 0.f); acc.w += fmaxf(p.w + bf2f(q2.w), 0.f);
      acc.x += fmaxf(p.x + bf2f(q3.x), 0.f); acc.y += fmaxf(p.y + bf2f(q3.y), 0.f);
      acc.z += fmaxf(p.z + bf2f(q3.z), 0.f); acc.w += fmaxf(p.w + bf2f(q3.w), 0.f);
    }
    for (; j < m; ++j) {
      int c2 = sl[j];
      ushort4 q = ((const ushort4*)(Qb + (size_t)c2 * F_OUT))[lane];
      acc.x += fmaxf(p.x + bf2f(q.x), 0.f); acc.y += fmaxf(p.y + bf2f(q.y), 0.f);
      acc.z += fmaxf(p.z + bf2f(q.z), 0.f); acc.w += fmaxf(p.w + bf2f(q.w), 0.f);
    }
  }

  const float inv = 1.0f / (float)(deg > 1 ? deg : 1);
  float4 o = make_float4(acc.x * inv, acc.y * inv, acc.z * inv, acc.w * inv);
  ((float4*)(out + (size_t)n * F_OUT))[lane] = o;
}

extern "C" void kernel_launch(void* const* d_in, const int* in_sizes, int n_in,
                              void* d_out, int out_size, void* d_ws, size_t ws_size,
                              hipStream_t stream) {
  const float* x = (const float*)d_in[0];
  const unsigned int* eraw = (const unsigned int*)d_in[1];
  const float* W = (const float*)d_in[2];
  const float* b = (const float*)d_in[3];
  float* out = (float*)d_out;

  char* ws = (char*)d_ws;
  float* P              = (float*)(ws);                      // 25,600,000 B
  unsigned short* Qb    = (unsigned short*)(ws + 25600000);  // 12,800,000 B
  int* cnt              = (int*)(ws + 38400000);             // 8*50000*4 = 1,600,000 B
  unsigned short* slots = (unsigned short*)(ws + 40000000);  // 8*50000*24*2 = 19,200,000 B

  hipMemsetAsync(cnt, 0, sizeof(int) * NPART * N_NODES, stream);

  fused_gemm_bucket_kernel<<<BUCKET_BLOCKS + GEMM_BLOCKS, 256, 0, stream>>>(
      x, W, b, eraw, P, Qb, cnt, slots);
  aggregate_kernel<<<N_NODES / 8, 256, 0, stream>>>(P, Qb, slots, cnt, out);
}

// Round 5
// 148.887 us; speedup vs baseline: 1.0401x; 1.0401x over previous
//
#include <hip/hip_runtime.h>

#define N_NODES 50000
#define F_IN 64
#define F_OUT 128
#define N_EDGES 800000

#define CAP 48          // u16 slots per node; max deg ~40 (Poisson(16), 50K draws)
#define CAPW (CAP / 2)  // packed u32 words per node
#define BUCKET_BLOCKS 2048
#define GROWS 16
#define GEMM_BLOCKS (N_NODES / GROWS)   // 3125

__device__ __forceinline__ unsigned short f2bf(float f) {
  unsigned u = __float_as_uint(f);
  unsigned r = u + 0x7FFF + ((u >> 16) & 1);   // round-to-nearest-even
  return (unsigned short)(r >> 16);
}
__device__ __forceinline__ float bf2f(unsigned short h) {
  return __uint_as_float((unsigned)h << 16);
}

// ---------------------------------------------------------------------------
// One launch, two block roles on disjoint resources (memory-atomic vs
// VALU/LDS) so they overlap:
//
//  blocks [0, BUCKET_BLOCKS): bucket edges by destination row.
//    pos = atomicAdd(cnt[r]) (returning, ~16B HBM each);
//    col packed 2-per-u32 via fire-and-forget atomicOr (~16B HBM each,
//    vs ~55B/line for scattered u16 stores — round-3 counter evidence).
//
//  blocks [BUCKET_BLOCKS, +GEMM_BLOCKS): node projections,
//    P[n] = (W1 - W2).x[n] + b (f32), Qb[n] = W2.x[n] (bf16).
//    128 threads; thread j owns BOTH P-col j and Q-col j (2 cols/thread
//    halves LDS-read instrs per FMA — round-3 GEMM was LDS-BW-bound).
//    Weight cols in explicit float4 reg arrays; 4 independent row chains.
// ---------------------------------------------------------------------------
__global__ __launch_bounds__(128) void fused_gemm_bucket_kernel(
    const float* __restrict__ x, const float* __restrict__ W,
    const float* __restrict__ b, const unsigned int* __restrict__ eraw,
    float* __restrict__ P, unsigned short* __restrict__ Qb,
    int* __restrict__ cnt, unsigned int* __restrict__ slotw) {
  const int tid = threadIdx.x;

  if (blockIdx.x < BUCKET_BLOCKS) {
    // int64 LE (values < 2^31) -> odd 32-bit words all zero; int32 random
    // indices -> all-zero probability ~ (2e-5)^4.
    const bool is64 = ((eraw[1] | eraw[3] | eraw[5] | eraw[7]) == 0u);
    const int stride = BUCKET_BLOCKS * 128;
    for (int e = blockIdx.x * 128 + tid; e < N_EDGES; e += stride) {
      int r = (int)(is64 ? eraw[2 * (size_t)e] : eraw[e]);
      int c = (int)(is64 ? eraw[2 * ((size_t)N_EDGES + e)] : eraw[N_EDGES + e]);
      int pos = atomicAdd(&cnt[r], 1);
      if (pos < CAP) {
        unsigned val = (unsigned)c << (16 * (pos & 1));
        atomicOr(&slotw[r * CAPW + (pos >> 1)], val);
      }
    }
    return;
  }

  __shared__ float xs[GROWS][F_IN];   // 4 KiB
  const int gb = blockIdx.x - BUCKET_BLOCKS;
  const int row0 = gb * GROWS;        // 50000 % 16 == 0

  {  // stage 16x64 f32: 128 threads x 8 floats
    int r = tid >> 3, k8 = (tid & 7) * 8;
    const float* src = &x[(size_t)(row0 + r) * F_IN + k8];
    *(float4*)&xs[r][k8] = *(const float4*)src;
    *(float4*)&xs[r][k8 + 4] = *(const float4*)(src + 4);
  }
  __syncthreads();

  // thread tid owns P column tid and Q column tid
  float4 wp4[16], wq4[16];
#pragma unroll
  for (int k4 = 0; k4 < 16; ++k4) {
    float4 w1 = *(const float4*)&W[tid * (2 * F_IN) + k4 * 4];
    float4 w2 = *(const float4*)&W[tid * (2 * F_IN) + F_IN + k4 * 4];
    wp4[k4] = make_float4(w1.x - w2.x, w1.y - w2.y, w1.z - w2.z, w1.w - w2.w);
    wq4[k4] = w2;
  }
  const float bias = b[tid];

  for (int r0 = 0; r0 < GROWS; r0 += 4) {
    float sp0 = bias, sp1 = bias, sp2 = bias, sp3 = bias;
    float sq0 = 0.f, sq1 = 0.f, sq2 = 0.f, sq3 = 0.f;
#pragma unroll
    for (int k4 = 0; k4 < 16; ++k4) {
      float4 a0 = *(const float4*)&xs[r0 + 0][k4 * 4];
      float4 a1 = *(const float4*)&xs[r0 + 1][k4 * 4];
      float4 a2 = *(const float4*)&xs[r0 + 2][k4 * 4];
      float4 a3 = *(const float4*)&xs[r0 + 3][k4 * 4];
      const float4 wp = wp4[k4], wq = wq4[k4];
      sp0 = fmaf(a0.x, wp.x, sp0); sq0 = fmaf(a0.x, wq.x, sq0);
      sp1 = fmaf(a1.x, wp.x, sp1); sq1 = fmaf(a1.x, wq.x, sq1);
      sp2 = fmaf(a2.x, wp.x, sp2); sq2 = fmaf(a2.x, wq.x, sq2);
      sp3 = fmaf(a3.x, wp.x, sp3); sq3 = fmaf(a3.x, wq.x, sq3);
      sp0 = fmaf(a0.y, wp.y, sp0); sq0 = fmaf(a0.y, wq.y, sq0);
      sp1 = fmaf(a1.y, wp.y, sp1); sq1 = fmaf(a1.y, wq.y, sq1);
      sp2 = fmaf(a2.y, wp.y, sp2); sq2 = fmaf(a2.y, wq.y, sq2);
      sp3 = fmaf(a3.y, wp.y, sp3); sq3 = fmaf(a3.y, wq.y, sq3);
      sp0 = fmaf(a0.z, wp.z, sp0); sq0 = fmaf(a0.z, wq.z, sq0);
      sp1 = fmaf(a1.z, wp.z, sp1); sq1 = fmaf(a1.z, wq.z, sq1);
      sp2 = fmaf(a2.z, wp.z, sp2); sq2 = fmaf(a2.z, wq.z, sq2);
      sp3 = fmaf(a3.z, wp.z, sp3); sq3 = fmaf(a3.z, wq.z, sq3);
      sp0 = fmaf(a0.w, wp.w, sp0); sq0 = fmaf(a0.w, wq.w, sq0);
      sp1 = fmaf(a1.w, wp.w, sp1); sq1 = fmaf(a1.w, wq.w, sq1);
      sp2 = fmaf(a2.w, wp.w, sp2); sq2 = fmaf(a2.w, wq.w, sq2);
      sp3 = fmaf(a3.w, wp.w, sp3); sq3 = fmaf(a3.w, wq.w, sq3);
    }
    P[(size_t)(row0 + r0 + 0) * F_OUT + tid] = sp0;
    P[(size_t)(row0 + r0 + 1) * F_OUT + tid] = sp1;
    P[(size_t)(row0 + r0 + 2) * F_OUT + tid] = sp2;
    P[(size_t)(row0 + r0 + 3) * F_OUT + tid] = sp3;
    Qb[(size_t)(row0 + r0 + 0) * F_OUT + tid] = f2bf(sq0);
    Qb[(size_t)(row0 + r0 + 1) * F_OUT + tid] = f2bf(sq1);
    Qb[(size_t)(row0 + r0 + 2) * F_OUT + tid] = f2bf(sq2);
    Qb[(size_t)(row0 + r0 + 3) * F_OUT + tid] = f2bf(sq3);
  }
}

// ---------------------------------------------------------------------------
// Per node n: out[n] = (1/max(deg,1)) * sum_j relu(P[n] + Q[col_j]).
// 32 lanes per node (float4 each), 8 nodes per 256-thr block; cols unpacked
// from u32 pairs; 4 gathers in flight.
// ---------------------------------------------------------------------------
__global__ __launch_bounds__(256) void aggregate_kernel(
    const float* __restrict__ P, const unsigned short* __restrict__ Qb,
    const unsigned int* __restrict__ slotw, const int* __restrict__ cnt,
    float* __restrict__ out) {
  const int tid = threadIdx.x;
  const int lane = tid & 31;
  const int n = blockIdx.x * 8 + (tid >> 5);   // grid covers exactly N_NODES

  const int deg = cnt[n];
  const int m = min(deg, CAP);
  const float4 p = ((const float4*)(P + (size_t)n * F_OUT))[lane];
  const unsigned int* sw = slotw + (size_t)n * CAPW;

  float4 acc = make_float4(0.f, 0.f, 0.f, 0.f);
  int j = 0;
  for (; j + 4 <= m; j += 4) {
    unsigned w0 = sw[(j >> 1) + 0];
    unsigned w1 = sw[(j >> 1) + 1];
    int c0 = w0 & 0xFFFF, c1 = w0 >> 16, c2 = w1 & 0xFFFF, c3 = w1 >> 16;
    ushort4 q0 = ((const ushort4*)(Qb + (size_t)c0 * F_OUT))[lane];
    ushort4 q1 = ((const ushort4*)(Qb + (size_t)c1 * F_OUT))[lane];
    ushort4 q2 = ((const ushort4*)(Qb + (size_t)c2 * F_OUT))[lane];
    ushort4 q3 = ((const ushort4*)(Qb + (size_t)c3 * F_OUT))[lane];
    acc.x += fmaxf(p.x + bf2f(q0.x), 0.f); acc.y += fmaxf(p.y + bf2f(q0.y), 0.f);
    acc.z += fmaxf(p.z + bf2f(q0.z), 0.f); acc.w += fmaxf(p.w + bf2f(q0.w), 0.f);
    acc.x += fmaxf(p.x + bf2f(q1.x), 0.f); acc.y += fmaxf(p.y + bf2f(q1.y), 0.f);
    acc.z += fmaxf(p.z + bf2f(q1.z), 0.f); acc.w += fmaxf(p.w + bf2f(q1.w), 0.f);
    acc.x += fmaxf(p.x + bf2f(q2.x), 0.f); acc.y += fmaxf(p.y + bf2f(q2.y), 0.f);
    acc.z += fmaxf(p.z + bf2f(q2.z), 0.f); acc.w += fmaxf(p.w + bf2f(q2.w), 0.f);
    acc.x += fmaxf(p.x + bf2f(q3.x), 0.f); acc.y += fmaxf(p.y + bf2f(q3.y), 0.f);
    acc.z += fmaxf(p.z + bf2f(q3.z), 0.f); acc.w += fmaxf(p.w + bf2f(q3.w), 0.f);
  }
  for (; j < m; ++j) {
    unsigned w = sw[j >> 1];
    int c = (j & 1) ? (int)(w >> 16) : (int)(w & 0xFFFF);
    ushort4 q = ((const ushort4*)(Qb + (size_t)c * F_OUT))[lane];
    acc.x += fmaxf(p.x + bf2f(q.x), 0.f); acc.y += fmaxf(p.y + bf2f(q.y), 0.f);
    acc.z += fmaxf(p.z + bf2f(q.z), 0.f); acc.w += fmaxf(p.w + bf2f(q.w), 0.f);
  }

  const float inv = 1.0f / (float)(deg > 1 ? deg : 1);
  float4 o = make_float4(acc.x * inv, acc.y * inv, acc.z * inv, acc.w * inv);
  ((float4*)(out + (size_t)n * F_OUT))[lane] = o;
}

extern "C" void kernel_launch(void* const* d_in, const int* in_sizes, int n_in,
                              void* d_out, int out_size, void* d_ws, size_t ws_size,
                              hipStream_t stream) {
  const float* x = (const float*)d_in[0];
  const unsigned int* eraw = (const unsigned int*)d_in[1];
  const float* W = (const float*)d_in[2];
  const float* b = (const float*)d_in[3];
  float* out = (float*)d_out;

  char* ws = (char*)d_ws;
  float* P            = (float*)(ws);                      // 25,600,000 B
  unsigned short* Qb  = (unsigned short*)(ws + 25600000);  // 12,800,000 B
  int* cnt            = (int*)(ws + 38400000);             //    200,000 B
  unsigned int* slotw = (unsigned int*)(ws + 38600000);    // 50000*24*4 = 4,800,000 B

  hipMemsetAsync(cnt, 0, sizeof(int) * N_NODES, stream);
  hipMemsetAsync(slotw, 0, sizeof(unsigned int) * N_NODES * CAPW, stream);

  fused_gemm_bucket_kernel<<<BUCKET_BLOCKS + GEMM_BLOCKS, 128, 0, stream>>>(
      x, W, b, eraw, P, Qb, cnt, slotw);
  aggregate_kernel<<<N_NODES / 8, 256, 0, stream>>>(P, Qb, slotw, cnt, out);
}

// Round 6
// 146.747 us; speedup vs baseline: 1.0553x; 1.0146x over previous
//
#include <hip/hip_runtime.h>

#define N_NODES 50000
#define F_IN 64
#define F_OUT 128
#define N_EDGES 800000

#define CAP 48          // u16 slots per node; P(Poisson(16) >= 48) * 50K ~ 3e-6
#define CAPW (CAP / 2)  // packed u32 words per node
#define BUCKET_BLOCKS 2048
#define GROWS 16
#define GEMM_BLOCKS (N_NODES / GROWS)   // 3125

__device__ __forceinline__ unsigned short f2bf(float f) {
  unsigned u = __float_as_uint(f);
  unsigned r = u + 0x7FFF + ((u >> 16) & 1);   // round-to-nearest-even
  return (unsigned short)(r >> 16);
}
__device__ __forceinline__ float bf2f(unsigned short h) {
  return __uint_as_float((unsigned)h << 16);
}

// ---------------------------------------------------------------------------
// One launch, two block roles on disjoint pipes (memory-side atomics vs
// VALU/LDS) so they overlap:
//
//  blocks [0, BUCKET_BLOCKS): bucket edges by destination row.
//    pos = atomicAdd(cnt[r]) (returning); col packed 2-per-u32 via
//    fire-and-forget atomicOr. ~1.6M memory-side ops ~= 22-40 us floor.
//
//  blocks [BUCKET_BLOCKS, +GEMM_BLOCKS): node projections,
//    P[n] = (W1 - W2).x[n] + b (f32), Qb[n] = W2.x[n] (bf16).
//    Thread j owns P-col j AND Q-col j. Weight cols (32 x float4 = 128 VGPR)
//    MUST stay resident: __launch_bounds__(128,2) lifts the VGPR cap to 256,
//    and "#pragma unroll 1" on the row loop forces the weights live across
//    iterations instead of being rematerialized per unrolled copy (the
//    round-4/5 failure mode; round-2's non-unrolled loop kept VGPR=112).
// ---------------------------------------------------------------------------
__global__ __launch_bounds__(128, 2) void fused_gemm_bucket_kernel(
    const float* __restrict__ x, const float* __restrict__ W,
    const float* __restrict__ b, const unsigned int* __restrict__ eraw,
    float* __restrict__ P, unsigned short* __restrict__ Qb,
    int* __restrict__ cnt, unsigned int* __restrict__ slotw) {
  const int tid = threadIdx.x;

  if (blockIdx.x < BUCKET_BLOCKS) {
    // int64 LE (values < 2^31) -> odd 32-bit words all zero; int32 random
    // indices -> all-zero probability ~ (2e-5)^4.
    const bool is64 = ((eraw[1] | eraw[3] | eraw[5] | eraw[7]) == 0u);
    const int stride = BUCKET_BLOCKS * 128;
    for (int e = blockIdx.x * 128 + tid; e < N_EDGES; e += stride) {
      int r = (int)(is64 ? eraw[2 * (size_t)e] : eraw[e]);
      int c = (int)(is64 ? eraw[2 * ((size_t)N_EDGES + e)] : eraw[N_EDGES + e]);
      int pos = atomicAdd(&cnt[r], 1);
      if (pos < CAP) {
        unsigned val = (unsigned)c << (16 * (pos & 1));
        atomicOr(&slotw[r * CAPW + (pos >> 1)], val);
      }
    }
    return;
  }

  __shared__ float xs[GROWS][F_IN];   // 4 KiB
  const int gb = blockIdx.x - BUCKET_BLOCKS;
  const int row0 = gb * GROWS;        // 50000 % 16 == 0

  // thread tid owns P column tid and Q column tid (issue before LDS staging
  // so the global loads overlap).
  float4 wp4[16], wq4[16];
#pragma unroll
  for (int k4 = 0; k4 < 16; ++k4) {
    float4 w1 = *(const float4*)&W[tid * (2 * F_IN) + k4 * 4];
    float4 w2 = *(const float4*)&W[tid * (2 * F_IN) + F_IN + k4 * 4];
    wp4[k4] = make_float4(w1.x - w2.x, w1.y - w2.y, w1.z - w2.z, w1.w - w2.w);
    wq4[k4] = w2;
  }
  const float bias = b[tid];

  {  // stage 16x64 f32: 128 threads x 8 floats
    int r = tid >> 3, k8 = (tid & 7) * 8;
    const float* src = &x[(size_t)(row0 + r) * F_IN + k8];
    float4 v0 = *(const float4*)src;
    float4 v1 = *(const float4*)(src + 4);
    *(float4*)&xs[r][k8] = v0;
    *(float4*)&xs[r][k8 + 4] = v1;
  }
  __syncthreads();

#pragma unroll 1
  for (int r0 = 0; r0 < GROWS; r0 += 4) {
    float sp0 = bias, sp1 = bias, sp2 = bias, sp3 = bias;
    float sq0 = 0.f, sq1 = 0.f, sq2 = 0.f, sq3 = 0.f;
#pragma unroll
    for (int k4 = 0; k4 < 16; ++k4) {
      float4 a0 = *(const float4*)&xs[r0 + 0][k4 * 4];
      float4 a1 = *(const float4*)&xs[r0 + 1][k4 * 4];
      float4 a2 = *(const float4*)&xs[r0 + 2][k4 * 4];
      float4 a3 = *(const float4*)&xs[r0 + 3][k4 * 4];
      const float4 wp = wp4[k4], wq = wq4[k4];
      sp0 = fmaf(a0.x, wp.x, sp0); sq0 = fmaf(a0.x, wq.x, sq0);
      sp1 = fmaf(a1.x, wp.x, sp1); sq1 = fmaf(a1.x, wq.x, sq1);
      sp2 = fmaf(a2.x, wp.x, sp2); sq2 = fmaf(a2.x, wq.x, sq2);
      sp3 = fmaf(a3.x, wp.x, sp3); sq3 = fmaf(a3.x, wq.x, sq3);
      sp0 = fmaf(a0.y, wp.y, sp0); sq0 = fmaf(a0.y, wq.y, sq0);
      sp1 = fmaf(a1.y, wp.y, sp1); sq1 = fmaf(a1.y, wq.y, sq1);
      sp2 = fmaf(a2.y, wp.y, sp2); sq2 = fmaf(a2.y, wq.y, sq2);
      sp3 = fmaf(a3.y, wp.y, sp3); sq3 = fmaf(a3.y, wq.y, sq3);
      sp0 = fmaf(a0.z, wp.z, sp0); sq0 = fmaf(a0.z, wq.z, sq0);
      sp1 = fmaf(a1.z, wp.z, sp1); sq1 = fmaf(a1.z, wq.z, sq1);
      sp2 = fmaf(a2.z, wp.z, sp2); sq2 = fmaf(a2.z, wq.z, sq2);
      sp3 = fmaf(a3.z, wp.z, sp3); sq3 = fmaf(a3.z, wq.z, sq3);
      sp0 = fmaf(a0.w, wp.w, sp0); sq0 = fmaf(a0.w, wq.w, sq0);
      sp1 = fmaf(a1.w, wp.w, sp1); sq1 = fmaf(a1.w, wq.w, sq1);
      sp2 = fmaf(a2.w, wp.w, sp2); sq2 = fmaf(a2.w, wq.w, sq2);
      sp3 = fmaf(a3.w, wp.w, sp3); sq3 = fmaf(a3.w, wq.w, sq3);
    }
    P[(size_t)(row0 + r0 + 0) * F_OUT + tid] = sp0;
    P[(size_t)(row0 + r0 + 1) * F_OUT + tid] = sp1;
    P[(size_t)(row0 + r0 + 2) * F_OUT + tid] = sp2;
    P[(size_t)(row0 + r0 + 3) * F_OUT + tid] = sp3;
    Qb[(size_t)(row0 + r0 + 0) * F_OUT + tid] = f2bf(sq0);
    Qb[(size_t)(row0 + r0 + 1) * F_OUT + tid] = f2bf(sq1);
    Qb[(size_t)(row0 + r0 + 2) * F_OUT + tid] = f2bf(sq2);
    Qb[(size_t)(row0 + r0 + 3) * F_OUT + tid] = f2bf(sq3);
  }
}

// ---------------------------------------------------------------------------
// Per node n: out[n] = (1/max(deg,1)) * sum_j relu(P[n] + Q[col_j]).
// 32 lanes per node (float4 each), 8 nodes per 256-thr block; cols unpacked
// from u32 pairs; 4 gathers in flight.
// ---------------------------------------------------------------------------
__global__ __launch_bounds__(256) void aggregate_kernel(
    const float* __restrict__ P, const unsigned short* __restrict__ Qb,
    const unsigned int* __restrict__ slotw, const int* __restrict__ cnt,
    float* __restrict__ out) {
  const int tid = threadIdx.x;
  const int lane = tid & 31;
  const int n = blockIdx.x * 8 + (tid >> 5);   // grid covers exactly N_NODES

  const int deg = cnt[n];
  const int m = min(deg, CAP);
  const float4 p = ((const float4*)(P + (size_t)n * F_OUT))[lane];
  const unsigned int* sw = slotw + (size_t)n * CAPW;

  float4 acc = make_float4(0.f, 0.f, 0.f, 0.f);
  int j = 0;
  for (; j + 4 <= m; j += 4) {
    unsigned w0 = sw[(j >> 1) + 0];
    unsigned w1 = sw[(j >> 1) + 1];
    int c0 = w0 & 0xFFFF, c1 = w0 >> 16, c2 = w1 & 0xFFFF, c3 = w1 >> 16;
    ushort4 q0 = ((const ushort4*)(Qb + (size_t)c0 * F_OUT))[lane];
    ushort4 q1 = ((const ushort4*)(Qb + (size_t)c1 * F_OUT))[lane];
    ushort4 q2 = ((const ushort4*)(Qb + (size_t)c2 * F_OUT))[lane];
    ushort4 q3 = ((const ushort4*)(Qb + (size_t)c3 * F_OUT))[lane];
    acc.x += fmaxf(p.x + bf2f(q0.x), 0.f); acc.y += fmaxf(p.y + bf2f(q0.y), 0.f);
    acc.z += fmaxf(p.z + bf2f(q0.z), 0.f); acc.w += fmaxf(p.w + bf2f(q0.w), 0.f);
    acc.x += fmaxf(p.x + bf2f(q1.x), 0.f); acc.y += fmaxf(p.y + bf2f(q1.y), 0.f);
    acc.z += fmaxf(p.z + bf2f(q1.z), 0.f); acc.w += fmaxf(p.w + bf2f(q1.w), 0.f);
    acc.x += fmaxf(p.x + bf2f(q2.x), 0.f); acc.y += fmaxf(p.y + bf2f(q2.y), 0.f);
    acc.z += fmaxf(p.z + bf2f(q2.z), 0.f); acc.w += fmaxf(p.w + bf2f(q2.w), 0.f);
    acc.x += fmaxf(p.x + bf2f(q3.x), 0.f); acc.y += fmaxf(p.y + bf2f(q3.y), 0.f);
    acc.z += fmaxf(p.z + bf2f(q3.z), 0.f); acc.w += fmaxf(p.w + bf2f(q3.w), 0.f);
  }
  for (; j < m; ++j) {
    unsigned w = sw[j >> 1];
    int c = (j & 1) ? (int)(w >> 16) : (int)(w & 0xFFFF);
    ushort4 q = ((const ushort4*)(Qb + (size_t)c * F_OUT))[lane];
    acc.x += fmaxf(p.x + bf2f(q.x), 0.f); acc.y += fmaxf(p.y + bf2f(q.y), 0.f);
    acc.z += fmaxf(p.z + bf2f(q.z), 0.f); acc.w += fmaxf(p.w + bf2f(q.w), 0.f);
  }

  const float inv = 1.0f / (float)(deg > 1 ? deg : 1);
  float4 o = make_float4(acc.x * inv, acc.y * inv, acc.z * inv, acc.w * inv);
  ((float4*)(out + (size_t)n * F_OUT))[lane] = o;
}

extern "C" void kernel_launch(void* const* d_in, const int* in_sizes, int n_in,
                              void* d_out, int out_size, void* d_ws, size_t ws_size,
                              hipStream_t stream) {
  const float* x = (const float*)d_in[0];
  const unsigned int* eraw = (const unsigned int*)d_in[1];
  const float* W = (const float*)d_in[2];
  const float* b = (const float*)d_in[3];
  float* out = (float*)d_out;

  char* ws = (char*)d_ws;
  float* P            = (float*)(ws);                      // 25,600,000 B
  unsigned short* Qb  = (unsigned short*)(ws + 25600000);  // 12,800,000 B
  int* cnt            = (int*)(ws + 38400000);             //    200,000 B
  unsigned int* slotw = (unsigned int*)(ws + 38600000);    // 50000*24*4 = 4,800,000 B

  hipMemsetAsync(cnt, 0, sizeof(int) * N_NODES, stream);
  hipMemsetAsync(slotw, 0, sizeof(unsigned int) * N_NODES * CAPW, stream);

  fused_gemm_bucket_kernel<<<BUCKET_BLOCKS + GEMM_BLOCKS, 128, 0, stream>>>(
      x, W, b, eraw, P, Qb, cnt, slotw);
  aggregate_kernel<<<N_NODES / 8, 256, 0, stream>>>(P, Qb, slotw, cnt, out);
}

// Round 7
// 146.012 us; speedup vs baseline: 1.0606x; 1.0050x over previous
//
#include <hip/hip_runtime.h>

#define N_NODES 50000
#define F_IN 64
#define F_OUT 128
#define N_EDGES 800000

#define CAP 48          // u16 slots per node; P(Poisson(16) >= 48)*50K ~ 3e-6
#define CAPW (CAP / 2)  // packed u32 words per node
#define BUCKET_BLOCKS 1024
#define XCONV_BLOCKS 1563          // ceil(3.2M / (256*8))
#define NRT (N_NODES / 16)         // 3125 row-tiles of 16 nodes
#define GEMM_WAVES 4

typedef __attribute__((ext_vector_type(8))) short bf16x8;  // 8 bf16 = 4 VGPR
typedef __attribute__((ext_vector_type(4))) float f32x4;

__device__ __forceinline__ unsigned short f2bf(float f) {
  unsigned u = __float_as_uint(f);
  unsigned r = u + 0x7FFF + ((u >> 16) & 1);   // round-to-nearest-even
  return (unsigned short)(r >> 16);
}
__device__ __forceinline__ float bf2f(unsigned short h) {
  return __uint_as_float((unsigned)h << 16);
}

// ---------------------------------------------------------------------------
// Convert x -> bf16 (Xb, row-major [node][64]) and build folded weight
// Wcb[256][64] bf16: col j<128 -> W1[j]-W2[j], j>=128 -> W2[j-128].
// ---------------------------------------------------------------------------
__global__ __launch_bounds__(256) void convert_kernel(
    const float* __restrict__ x, const float* __restrict__ W,
    unsigned short* __restrict__ Xb, unsigned short* __restrict__ Wcb) {
  const int bid = blockIdx.x;
  if (bid < XCONV_BLOCKS) {
    int i = (bid * 256 + threadIdx.x) * 8;
    if (i < N_NODES * F_IN) {
      float4 v0 = *(const float4*)&x[i];
      float4 v1 = *(const float4*)&x[i + 4];
      ushort4 o0 = {f2bf(v0.x), f2bf(v0.y), f2bf(v0.z), f2bf(v0.w)};
      ushort4 o1 = {f2bf(v1.x), f2bf(v1.y), f2bf(v1.z), f2bf(v1.w)};
      *(ushort4*)&Xb[i] = o0;
      *(ushort4*)&Xb[i + 4] = o1;
    }
  } else {
    int idx = (bid - XCONV_BLOCKS) * 256 + threadIdx.x;   // 0..16383
    int j = idx >> 6, k = idx & 63;
    float v = (j < F_OUT)
                  ? W[j * (2 * F_IN) + k] - W[j * (2 * F_IN) + F_IN + k]
                  : W[(j - F_OUT) * (2 * F_IN) + F_IN + k];
    Wcb[idx] = f2bf(v);
  }
}

// ---------------------------------------------------------------------------
// Bucket edges by destination row. pos = atomicAdd(cnt[r]) (returning);
// col packed 2-per-u32 via fire-and-forget atomicOr. Standalone this round
// so rocprof attributes its true cost.
// ---------------------------------------------------------------------------
__global__ __launch_bounds__(256) void bucket_kernel(
    const unsigned int* __restrict__ eraw, int* __restrict__ cnt,
    unsigned int* __restrict__ slotw) {
  // int64 LE (values < 2^31) -> odd 32-bit words all zero; int32 random
  // indices -> all-zero probability ~ (2e-5)^4.
  const bool is64 = ((eraw[1] | eraw[3] | eraw[5] | eraw[7]) == 0u);
  const int stride = BUCKET_BLOCKS * 256;
  for (int e = blockIdx.x * 256 + threadIdx.x; e < N_EDGES; e += stride) {
    int r = (int)(is64 ? eraw[2 * (size_t)e] : eraw[e]);
    int c = (int)(is64 ? eraw[2 * ((size_t)N_EDGES + e)] : eraw[N_EDGES + e]);
    int pos = atomicAdd(&cnt[r], 1);
    if (pos < CAP) {
      unsigned val = (unsigned)c << (16 * (pos & 1));
      atomicOr(&slotw[r * CAPW + (pos >> 1)], val);
    }
  }
}

// ---------------------------------------------------------------------------
// MFMA GEMM: Y[50000x256] = Xb[50000x64] @ Wcb^T, via mfma_f32_16x16x32_bf16.
// One wave = one 16-node row-tile x all 256 cols (16 col-tiles x 2 K-halves).
// Fragments loaded directly from global (A: row=lane&15, k=8*(lane>>4)+i;
// B: col=lane&15, same k; C/D: col=lane&15, row=4*(lane>>4)+reg — m89 layout).
// P (cols 0..127, +bias) stored f32; Q (cols 128..255) stored bf16.
// Accumulator lives in AGPRs — nothing for the register allocator to spill.
// ---------------------------------------------------------------------------
__global__ __launch_bounds__(256) void gemm_mfma_kernel(
    const unsigned short* __restrict__ Xb, const unsigned short* __restrict__ Wcb,
    const float* __restrict__ b, float* __restrict__ P,
    unsigned short* __restrict__ Qb) {
  const int tid = threadIdx.x;
  const int lane = tid & 63;
  const int wid = tid >> 6;
  const int rt = blockIdx.x * GEMM_WAVES + wid;
  if (rt >= NRT) return;

  const int l15 = lane & 15;
  const int lk = (lane >> 4) * 8;

  const unsigned short* xrow = Xb + ((size_t)rt * 16 + l15) * F_IN;
  bf16x8 a0 = *(const bf16x8*)(xrow + lk);        // k 0..31
  bf16x8 a1 = *(const bf16x8*)(xrow + 32 + lk);   // k 32..63

#pragma unroll
  for (int ct = 0; ct < 16; ++ct) {
    const unsigned short* wcol = Wcb + (size_t)(ct * 16 + l15) * F_IN;
    bf16x8 b0 = *(const bf16x8*)(wcol + lk);
    bf16x8 b1 = *(const bf16x8*)(wcol + 32 + lk);
    const float bias = (ct < 8) ? b[ct * 16 + l15] : 0.f;
    f32x4 acc = {bias, bias, bias, bias};
    acc = __builtin_amdgcn_mfma_f32_16x16x32_bf16(a0, b0, acc, 0, 0, 0);
    acc = __builtin_amdgcn_mfma_f32_16x16x32_bf16(a1, b1, acc, 0, 0, 0);
#pragma unroll
    for (int r = 0; r < 4; ++r) {
      const int node = rt * 16 + (lane >> 4) * 4 + r;
      if (ct < 8) {
        P[(size_t)node * F_OUT + ct * 16 + l15] = acc[r];
      } else {
        Qb[(size_t)node * F_OUT + (ct - 8) * 16 + l15] = f2bf(acc[r]);
      }
    }
  }
}

// ---------------------------------------------------------------------------
// Per node n: out[n] = (1/max(deg,1)) * sum_j relu(P[n] + Q[col_j]).
// 32 lanes per node (float4 each), 8 nodes per 256-thr block; cols unpacked
// from u32 pairs; 4 gathers in flight.
// ---------------------------------------------------------------------------
__global__ __launch_bounds__(256) void aggregate_kernel(
    const float* __restrict__ P, const unsigned short* __restrict__ Qb,
    const unsigned int* __restrict__ slotw, const int* __restrict__ cnt,
    float* __restrict__ out) {
  const int tid = threadIdx.x;
  const int lane = tid & 31;
  const int n = blockIdx.x * 8 + (tid >> 5);   // grid covers exactly N_NODES

  const int deg = cnt[n];
  const int m = min(deg, CAP);
  const float4 p = ((const float4*)(P + (size_t)n * F_OUT))[lane];
  const unsigned int* sw = slotw + (size_t)n * CAPW;

  float4 acc = make_float4(0.f, 0.f, 0.f, 0.f);
  int j = 0;
  for (; j + 4 <= m; j += 4) {
    unsigned w0 = sw[(j >> 1) + 0];
    unsigned w1 = sw[(j >> 1) + 1];
    int c0 = w0 & 0xFFFF, c1 = w0 >> 16, c2 = w1 & 0xFFFF, c3 = w1 >> 16;
    ushort4 q0 = ((const ushort4*)(Qb + (size_t)c0 * F_OUT))[lane];
    ushort4 q1 = ((const ushort4*)(Qb + (size_t)c1 * F_OUT))[lane];
    ushort4 q2 = ((const ushort4*)(Qb + (size_t)c2 * F_OUT))[lane];
    ushort4 q3 = ((const ushort4*)(Qb + (size_t)c3 * F_OUT))[lane];
    acc.x += fmaxf(p.x + bf2f(q0.x), 0.f); acc.y += fmaxf(p.y + bf2f(q0.y), 0.f);
    acc.z += fmaxf(p.z + bf2f(q0.z), 0.f); acc.w += fmaxf(p.w + bf2f(q0.w), 0.f);
    acc.x += fmaxf(p.x + bf2f(q1.x), 0.f); acc.y += fmaxf(p.y + bf2f(q1.y), 0.f);
    acc.z += fmaxf(p.z + bf2f(q1.z), 0.f); acc.w += fmaxf(p.w + bf2f(q1.w), 0.f);
    acc.x += fmaxf(p.x + bf2f(q2.x), 0.f); acc.y += fmaxf(p.y + bf2f(q2.y), 0.f);
    acc.z += fmaxf(p.z + bf2f(q2.z), 0.f); acc.w += fmaxf(p.w + bf2f(q2.w), 0.f);
    acc.x += fmaxf(p.x + bf2f(q3.x), 0.f); acc.y += fmaxf(p.y + bf2f(q3.y), 0.f);
    acc.z += fmaxf(p.z + bf2f(q3.z), 0.f); acc.w += fmaxf(p.w + bf2f(q3.w), 0.f);
  }
  for (; j < m; ++j) {
    unsigned w = sw[j >> 1];
    int c = (j & 1) ? (int)(w >> 16) : (int)(w & 0xFFFF);
    ushort4 q = ((const ushort4*)(Qb + (size_t)c * F_OUT))[lane];
    acc.x += fmaxf(p.x + bf2f(q.x), 0.f); acc.y += fmaxf(p.y + bf2f(q.y), 0.f);
    acc.z += fmaxf(p.z + bf2f(q.z), 0.f); acc.w += fmaxf(p.w + bf2f(q.w), 0.f);
  }

  const float inv = 1.0f / (float)(deg > 1 ? deg : 1);
  float4 o = make_float4(acc.x * inv, acc.y * inv, acc.z * inv, acc.w * inv);
  ((float4*)(out + (size_t)n * F_OUT))[lane] = o;
}

extern "C" void kernel_launch(void* const* d_in, const int* in_sizes, int n_in,
                              void* d_out, int out_size, void* d_ws, size_t ws_size,
                              hipStream_t stream) {
  const float* x = (const float*)d_in[0];
  const unsigned int* eraw = (const unsigned int*)d_in[1];
  const float* W = (const float*)d_in[2];
  const float* b = (const float*)d_in[3];
  float* out = (float*)d_out;

  char* ws = (char*)d_ws;
  float* P            = (float*)(ws);                      // 25,600,000 B
  unsigned short* Qb  = (unsigned short*)(ws + 25600000);  // 12,800,000 B
  int* cnt            = (int*)(ws + 38400000);             //    200,000 B
  unsigned int* slotw = (unsigned int*)(ws + 38600000);    //  4,800,000 B
  unsigned short* Xb  = (unsigned short*)(ws + 43400000);  //  6,400,000 B
  unsigned short* Wcb = (unsigned short*)(ws + 49800000);  //     32,768 B

  hipMemsetAsync(cnt, 0, sizeof(int) * N_NODES, stream);
  hipMemsetAsync(slotw, 0, sizeof(unsigned int) * N_NODES * CAPW, stream);

  convert_kernel<<<XCONV_BLOCKS + 64, 256, 0, stream>>>(x, W, Xb, Wcb);
  bucket_kernel<<<BUCKET_BLOCKS, 256, 0, stream>>>(eraw, cnt, slotw);
  gemm_mfma_kernel<<<(NRT + GEMM_WAVES - 1) / GEMM_WAVES, 256, 0, stream>>>(
      Xb, Wcb, b, P, Qb);
  aggregate_kernel<<<N_NODES / 8, 256, 0, stream>>>(P, Qb, slotw, cnt, out);
}

// Round 8
// 138.498 us; speedup vs baseline: 1.1182x; 1.0543x over previous
//
#include <hip/hip_runtime.h>

#define N_NODES 50000
#define F_IN 64
#define F_OUT 128
#define N_EDGES 800000

#define CAP 48                       // u16 slots per node; P(deg>=48) ~ 1e-11
#define BUCKET_BLOCKS 2048
#define NRT (N_NODES / 16)           // 3125 row-tiles of 16 nodes
#define GEMM_WAVES 4
#define GEMM_BLOCKS ((NRT + GEMM_WAVES - 1) / GEMM_WAVES)   // 782

typedef __attribute__((ext_vector_type(8))) short bf16x8;   // 8 bf16 = 4 VGPR
typedef __attribute__((ext_vector_type(4))) float f32x4;

__device__ __forceinline__ unsigned short f2bf(float f) {
  unsigned u = __float_as_uint(f);
  unsigned r = u + 0x7FFF + ((u >> 16) & 1);   // round-to-nearest-even
  return (unsigned short)(r >> 16);
}
__device__ __forceinline__ float bf2f(unsigned short h) {
  return __uint_as_float((unsigned)h << 16);
}
__device__ __forceinline__ float4 sub4(float4 a, float4 b) {
  return make_float4(a.x - b.x, a.y - b.y, a.z - b.z, a.w - b.w);
}
__device__ __forceinline__ bf16x8 cvt8(float4 p, float4 q) {
  bf16x8 r;
  r[0] = (short)f2bf(p.x); r[1] = (short)f2bf(p.y);
  r[2] = (short)f2bf(p.z); r[3] = (short)f2bf(p.w);
  r[4] = (short)f2bf(q.x); r[5] = (short)f2bf(q.y);
  r[6] = (short)f2bf(q.z); r[7] = (short)f2bf(q.w);
  return r;
}
#define L4(p) (*(const float4*)(p))

// ---------------------------------------------------------------------------
// One launch, two block roles on disjoint pipes (LLC atomics vs MFMA/memory)
// — same-stream dispatches serialize, so fusion is the only overlap path.
//
//  blocks [0, BUCKET_BLOCKS): bucket edges by destination row.
//    pos = atomicAdd(cnt[r]) (returning, the irreducible atomic);
//    col stored as PLAIN u16 store (round-3-proven: 56us; the round-7
//    atomicOr variant doubled LLC atomic messages -> 77us).
//
//  blocks [BUCKET_BLOCKS, +GEMM_BLOCKS): MFMA projections.
//    Pb[n] = bf16((W1 - W2).x[n] + b), Qb[n] = bf16(W2.x[n]).
//    One wave = 16-node row-tile x 256 cols (16 col-tiles x 2 MFMAs,
//    mfma_f32_16x16x32_bf16). x and W converted to bf16 fragments in-reg
//    (no staging buffers, no convert dispatch, nothing for the register
//    allocator to evict — the round-4/5/6 failure mode is structurally gone).
//    A: row=lane&15, k=8*(lane>>4)+i. B: col=lane&15, same k.
//    C/D: col=lane&15, row=4*(lane>>4)+reg (m89 layout, refcheck'd round 7).
// ---------------------------------------------------------------------------
__global__ __launch_bounds__(256) void fused_bucket_gemm_kernel(
    const float* __restrict__ x, const float* __restrict__ W,
    const float* __restrict__ b, const unsigned int* __restrict__ eraw,
    unsigned short* __restrict__ Pb, unsigned short* __restrict__ Qb,
    int* __restrict__ cnt, unsigned short* __restrict__ slots) {
  const int tid = threadIdx.x;

  if (blockIdx.x < BUCKET_BLOCKS) {
    // int64 LE (values < 2^31) -> odd 32-bit words all zero; int32 random
    // indices -> all-zero probability ~ (2e-5)^4.
    const bool is64 = ((eraw[1] | eraw[3] | eraw[5] | eraw[7]) == 0u);
    const int stride = BUCKET_BLOCKS * 256;
    for (int e = blockIdx.x * 256 + tid; e < N_EDGES; e += stride) {
      int r = (int)(is64 ? eraw[2 * (size_t)e] : eraw[e]);
      int c = (int)(is64 ? eraw[2 * ((size_t)N_EDGES + e)] : eraw[N_EDGES + e]);
      int pos = atomicAdd(&cnt[r], 1);
      if (pos < CAP) slots[(size_t)r * CAP + pos] = (unsigned short)c;
    }
    return;
  }

  const int lane = tid & 63;
  const int wid = tid >> 6;
  const int rt = (blockIdx.x - BUCKET_BLOCKS) * GEMM_WAVES + wid;
  if (rt >= NRT) return;

  const int l15 = lane & 15;
  const int lk = (lane >> 4) * 8;

  // A fragments: node row rt*16 + l15, k = lk..lk+7 (a0) and 32+lk.. (a1)
  const float* xrow = x + ((size_t)rt * 16 + l15) * F_IN;
  bf16x8 a0 = cvt8(L4(xrow + lk), L4(xrow + lk + 4));
  bf16x8 a1 = cvt8(L4(xrow + 32 + lk), L4(xrow + 36 + lk));

#pragma unroll
  for (int ct = 0; ct < 16; ++ct) {
    bf16x8 b0, b1;
    float bias = 0.f;
    if (ct < 8) {   // P columns: (W1 - W2) row ct*16+l15, + bias
      const float* wr = W + (size_t)(ct * 16 + l15) * (2 * F_IN);
      b0 = cvt8(sub4(L4(wr + lk), L4(wr + 64 + lk)),
                sub4(L4(wr + lk + 4), L4(wr + 68 + lk)));
      b1 = cvt8(sub4(L4(wr + 32 + lk), L4(wr + 96 + lk)),
                sub4(L4(wr + 36 + lk), L4(wr + 100 + lk)));
      bias = b[ct * 16 + l15];
    } else {        // Q columns: W2 row (ct-8)*16+l15
      const float* wr = W + (size_t)((ct - 8) * 16 + l15) * (2 * F_IN);
      b0 = cvt8(L4(wr + 64 + lk), L4(wr + 68 + lk));
      b1 = cvt8(L4(wr + 96 + lk), L4(wr + 100 + lk));
    }
    f32x4 acc = {bias, bias, bias, bias};
    acc = __builtin_amdgcn_mfma_f32_16x16x32_bf16(a0, b0, acc, 0, 0, 0);
    acc = __builtin_amdgcn_mfma_f32_16x16x32_bf16(a1, b1, acc, 0, 0, 0);

    unsigned short* dst = (ct < 8) ? Pb : Qb;
    const int col = (ct & 7) * 16 + l15;
#pragma unroll
    for (int r = 0; r < 4; ++r) {
      const int node = rt * 16 + (lane >> 4) * 4 + r;
      dst[(size_t)node * F_OUT + col] = f2bf(acc[r]);
    }
  }
}

// ---------------------------------------------------------------------------
// Per node n: out[n] = (1/max(deg,1)) * sum_j relu(P[n] + Q[col_j]).
// 32 lanes per node (4 feats each), 8 nodes per 256-thr block; P and Q both
// bf16 (8 B/lane gathers); 4 edges in flight for MLP.
// ---------------------------------------------------------------------------
__global__ __launch_bounds__(256) void aggregate_kernel(
    const unsigned short* __restrict__ Pb, const unsigned short* __restrict__ Qb,
    const unsigned short* __restrict__ slots, const int* __restrict__ cnt,
    float* __restrict__ out) {
  const int tid = threadIdx.x;
  const int lane = tid & 31;
  const int n = blockIdx.x * 8 + (tid >> 5);   // grid covers exactly N_NODES

  const int deg = cnt[n];
  const int m = min(deg, CAP);
  ushort4 pb = ((const ushort4*)(Pb + (size_t)n * F_OUT))[lane];
  const float px = bf2f(pb.x), py = bf2f(pb.y), pz = bf2f(pb.z), pw = bf2f(pb.w);
  const unsigned short* sl = slots + (size_t)n * CAP;

  float4 acc = make_float4(0.f, 0.f, 0.f, 0.f);
  int j = 0;
  for (; j + 4 <= m; j += 4) {
    ushort4 cs = *(const ushort4*)(sl + j);
    ushort4 q0 = ((const ushort4*)(Qb + (size_t)cs.x * F_OUT))[lane];
    ushort4 q1 = ((const ushort4*)(Qb + (size_t)cs.y * F_OUT))[lane];
    ushort4 q2 = ((const ushort4*)(Qb + (size_t)cs.z * F_OUT))[lane];
    ushort4 q3 = ((const ushort4*)(Qb + (size_t)cs.w * F_OUT))[lane];
    acc.x += fmaxf(px + bf2f(q0.x), 0.f); acc.y += fmaxf(py + bf2f(q0.y), 0.f);
    acc.z += fmaxf(pz + bf2f(q0.z), 0.f); acc.w += fmaxf(pw + bf2f(q0.w), 0.f);
    acc.x += fmaxf(px + bf2f(q1.x), 0.f); acc.y += fmaxf(py + bf2f(q1.y), 0.f);
    acc.z += fmaxf(pz + bf2f(q1.z), 0.f); acc.w += fmaxf(pw + bf2f(q1.w), 0.f);
    acc.x += fmaxf(px + bf2f(q2.x), 0.f); acc.y += fmaxf(py + bf2f(q2.y), 0.f);
    acc.z += fmaxf(pz + bf2f(q2.z), 0.f); acc.w += fmaxf(pw + bf2f(q2.w), 0.f);
    acc.x += fmaxf(px + bf2f(q3.x), 0.f); acc.y += fmaxf(py + bf2f(q3.y), 0.f);
    acc.z += fmaxf(pz + bf2f(q3.z), 0.f); acc.w += fmaxf(pw + bf2f(q3.w), 0.f);
  }
  for (; j < m; ++j) {
    int c = sl[j];
    ushort4 q = ((const ushort4*)(Qb + (size_t)c * F_OUT))[lane];
    acc.x += fmaxf(px + bf2f(q.x), 0.f); acc.y += fmaxf(py + bf2f(q.y), 0.f);
    acc.z += fmaxf(pz + bf2f(q.z), 0.f); acc.w += fmaxf(pw + bf2f(q.w), 0.f);
  }

  const float inv = 1.0f / (float)(deg > 1 ? deg : 1);
  float4 o = make_float4(acc.x * inv, acc.y * inv, acc.z * inv, acc.w * inv);
  ((float4*)(out + (size_t)n * F_OUT))[lane] = o;
}

extern "C" void kernel_launch(void* const* d_in, const int* in_sizes, int n_in,
                              void* d_out, int out_size, void* d_ws, size_t ws_size,
                              hipStream_t stream) {
  const float* x = (const float*)d_in[0];
  const unsigned int* eraw = (const unsigned int*)d_in[1];
  const float* W = (const float*)d_in[2];
  const float* b = (const float*)d_in[3];
  float* out = (float*)d_out;

  char* ws = (char*)d_ws;
  unsigned short* Pb    = (unsigned short*)(ws);             // 12,800,000 B
  unsigned short* Qb    = (unsigned short*)(ws + 12800000);  // 12,800,000 B
  int* cnt              = (int*)(ws + 25600000);             //    200,000 B
  unsigned short* slots = (unsigned short*)(ws + 25800000);  //  4,800,000 B

  hipMemsetAsync(cnt, 0, sizeof(int) * N_NODES, stream);

  fused_bucket_gemm_kernel<<<BUCKET_BLOCKS + GEMM_BLOCKS, 256, 0, stream>>>(
      x, W, b, eraw, Pb, Qb, cnt, slots);
  aggregate_kernel<<<N_NODES / 8, 256, 0, stream>>>(Pb, Qb, slots, cnt, out);
}